// Round 10
// baseline (186.530 us; speedup 1.0000x reference)
//
#include <hip/hip_runtime.h>

#define NB 32768

typedef _Float16 half8 __attribute__((ext_vector_type(8)));
typedef float floatx4 __attribute__((ext_vector_type(4)));
typedef float floatx2 __attribute__((ext_vector_type(2)));
typedef unsigned int uint4v __attribute__((ext_vector_type(4)));

#define MFMA16(a,b,c) __builtin_amdgcn_mfma_f32_16x16x32_f16(a,b,c,0,0,0)

// ---------- fast math ----------
__device__ __forceinline__ float rcp_f(float x){ return __builtin_amdgcn_rcpf(x); }
__device__ __forceinline__ float exp2_f(float x){ return __builtin_amdgcn_exp2f(x); }
__device__ __forceinline__ float tanh_f(float x){
  float e = exp2_f(x * 2.8853900817779268f);     // e^(2x)
  return (e - 1.0f) * rcp_f(e + 1.0f);
}
__device__ __forceinline__ float sigmoid_f(float x){
  return rcp_f(1.0f + exp2_f(-1.4426950408889634f * x));
}

// packed f32 math (VOP3P)
__device__ __forceinline__ floatx2 pk_mul2(floatx2 a, floatx2 b){
  floatx2 d; asm("v_pk_mul_f32 %0, %1, %2" : "=v"(d) : "v"(a), "v"(b)); return d;
}
__device__ __forceinline__ floatx2 pk_fma2(floatx2 a, floatx2 b, floatx2 c){
  floatx2 d; asm("v_pk_fma_f32 %0, %1, %2, %3" : "=v"(d) : "v"(a), "v"(b), "v"(c)); return d;
}

// DPP quad butterflies: xor1 = quad_perm[1,0,3,2]=0xB1, xor2 = [2,3,0,1]=0x4E
template<int CTRL>
__device__ __forceinline__ float dpp_qp(float x){
  return __builtin_bit_cast(float, __builtin_amdgcn_update_dpp(0, __builtin_bit_cast(int,x), CTRL, 0xF, 0xF, true));
}
__device__ __forceinline__ float qadd2(float x){
  x += dpp_qp<0xB1>(x);
  x += dpp_qp<0x4E>(x);
  return x;
}
__device__ __forceinline__ float qmax2(float x){
  x = fmaxf(x, dpp_qp<0xB1>(x));
  x = fmaxf(x, dpp_qp<0x4E>(x));
  return x;
}

// ---------- f16 weight region offsets (in _Float16 units), lives in d_ws ----------
constexpr int O_AW0H = 0;        // 256x128
constexpr int O_AW1H = 32768;    // 128x128
constexpr int O_AW2H = 49152;
constexpr int O_AW3H = 65536;    // 128x256
constexpr int O_PW0H = 98304;
constexpr int O_PW1H = 131072;
constexpr int O_PW2H = 147456;
constexpr int O_PW3H = 163840;   // 128x16
constexpr int O_AW1L = 165888;
constexpr int O_AW2L = 182272;
constexpr int O_AW3L = 198656;

// ---------- weight prep: LDS-tiled 64x64 transpose, coalesced read AND write ----
// Old version did ~234K scattered 2B global writes (one 32B sector each).
// New: read 64x64 f32 tile coalesced -> LDS [64][65] (bank-safe) -> write f16
// transposed, 64 consecutive k per wave = contiguous 128B stores.
struct PrepJob { const float* src; _Float16* h; _Float16* l; int K; int N; };
struct PrepJobs { PrepJob j[8]; };

__global__ __launch_bounds__(256) void prep_kernel(PrepJobs js){
  const PrepJob jb = js.j[blockIdx.y];
  const int tiles_n = (jb.N + 63) >> 6;
  const int tk = blockIdx.x / tiles_n;
  const int tn = blockIdx.x % tiles_n;
  if (tk * 64 >= jb.K) return;

  __shared__ unsigned int T[64][65];   // hi|lo packed, stride 65 kills bank conflicts
  const int lane = threadIdx.x & 63;
  const int row4 = threadIdx.x >> 6;

#pragma unroll 4
  for (int r = row4; r < 64; r += 4){
    const int k = tk*64 + r, n = tn*64 + lane;
    if (k < jb.K && n < jb.N){
      float w = jb.src[(long)k*jb.N + n];
      _Float16 h = (_Float16)w;
      _Float16 lo = (_Float16)(w - (float)h);
      T[r][lane] = (unsigned int)__builtin_bit_cast(unsigned short, h)
                 | ((unsigned int)__builtin_bit_cast(unsigned short, lo) << 16);
    }
  }
  __syncthreads();
#pragma unroll 4
  for (int r = row4; r < 64; r += 4){
    const int n = tn*64 + r, k = tk*64 + lane;
    if (n < jb.N && k < jb.K){
      unsigned int p = T[lane][r];            // transposed read, stride-65 = conflict-free
      jb.h[(long)n*jb.K + k] = __builtin_bit_cast(_Float16, (unsigned short)(p & 0xffffu));
      if (jb.l)
        jb.l[(long)n*jb.K + k] = __builtin_bit_cast(_Float16, (unsigned short)(p >> 16));
    }
  }
}

// ---------- LDS activation layout: 64 rows x 128 cols of packed (hi|lo) u32 ----------
// 16B-chunk XOR swizzle by (row&7)
__device__ __forceinline__ int aaddr(int row, int col){
  int cc = (col >> 2) ^ (row & 7);
  return row*128 + (cc<<2) + (col & 3);
}

template<bool NEED_LO>
__device__ __forceinline__ void read_frag(const unsigned int* __restrict__ act,
    int row, int ks, int q, half8& ah, half8& al)
{
  const int s = row & 7;
  const int cc0 = ks*8 + q*2;
  uint4v c0 = *(const uint4v*)(act + row*128 + (((cc0  ) ^ s)<<2));
  uint4v c1 = *(const uint4v*)(act + row*128 + (((cc0+1) ^ s)<<2));
  uint4v h;
  h.x = (c0.x & 0xffffu) | (c0.y << 16);
  h.y = (c0.z & 0xffffu) | (c0.w << 16);
  h.z = (c1.x & 0xffffu) | (c1.y << 16);
  h.w = (c1.z & 0xffffu) | (c1.w << 16);
  ah = __builtin_bit_cast(half8, h);
  if constexpr (NEED_LO){
    uint4v g;
    g.x = (c0.x >> 16) | (c0.y & 0xffff0000u);
    g.y = (c0.z >> 16) | (c0.w & 0xffff0000u);
    g.z = (c1.x >> 16) | (c1.y & 0xffff0000u);
    g.w = (c1.z >> 16) | (c1.w & 0xffff0000u);
    al = __builtin_bit_cast(half8, g);
  }
}

__device__ __forceinline__ unsigned int pack_act(float v){
  _Float16 h = (_Float16)v;
  _Float16 lo = (_Float16)(v - (float)h);
  return (unsigned int)__builtin_bit_cast(unsigned short, h)
       | ((unsigned int)__builtin_bit_cast(unsigned short, lo) << 16);
}
__device__ __forceinline__ unsigned int pack_act_hi(float v){
  return (unsigned int)__builtin_bit_cast(unsigned short, (_Float16)v);
}

// ---------- load one weight tile's fragments into a register stage ----------
template<int KS, bool LO>
__device__ __forceinline__ void load_tile(
    const _Float16* __restrict__ Wh, const _Float16* __restrict__ Wl,
    int K, int nt, int l15, int q, half8* bh, half8* bl)
{
  const _Float16* bp = Wh + (nt*16 + l15)*K + q*8;
#pragma unroll
  for (int ks=0; ks<KS; ++ks) bh[ks] = *(const half8*)(bp + ks*32);
  if constexpr (LO){
    const _Float16* blp = Wl + (nt*16 + l15)*K + q*8;
#pragma unroll
    for (int ks=0; ks<KS; ++ks) bl[ks] = *(const half8*)(blp + ks*32);
  }
}

// ---------- QUAD m-tile MFMA stream over n-tiles nt0..nt0+NT-1 ----------
// Each loaded B-frag feeds 4 MFMAs (4 m-tiles = 4-way acc ILP). Ring prefetch.
template<int KS, int PASSES, int NT, int RING, typename EPI>
__device__ __forceinline__ void mfma_stream4(
    const half8 (&Ah)[4][KS], const half8 (&Al)[4][KS],
    const _Float16* __restrict__ Wh, const _Float16* __restrict__ Wl,
    int K, int nt0, int l15, int q, EPI&& epi)
{
  half8 Bh[RING][KS], Bl[RING][KS];
  load_tile<KS,PASSES==3>(Wh, Wl, K, nt0, l15, q, Bh[0], Bl[0]);
  if constexpr (RING > 2){
    if constexpr (NT > 1)
      load_tile<KS,PASSES==3>(Wh, Wl, K, nt0+1, l15, q, Bh[1], Bl[1]);
  }
#pragma unroll
  for (int nt=0; nt<NT; ++nt){
    constexpr int PD = RING - 1;
    if (nt+PD < NT)
      load_tile<KS,PASSES==3>(Wh, Wl, K, nt0+nt+PD, l15, q, Bh[(nt+PD)%RING], Bl[(nt+PD)%RING]);
    floatx4 acc[4];
#pragma unroll
    for (int m=0; m<4; ++m) acc[m] = (floatx4)0.0f;
#pragma unroll
    for (int ks=0; ks<KS; ++ks){
      const half8 bh = Bh[nt%RING][ks];
#pragma unroll
      for (int m=0; m<4; ++m)
        acc[m] = MFMA16(Ah[m][ks], bh, acc[m]);
      if constexpr (PASSES == 3){
        const half8 bl = Bl[nt%RING][ks];
#pragma unroll
        for (int m=0; m<4; ++m){
          acc[m] = MFMA16(Al[m][ks], bh, acc[m]);
          acc[m] = MFMA16(Ah[m][ks], bl, acc[m]);
        }
      }
    }
    epi(nt0+nt, acc);
  }
}

// ================= Fused kernel: MLPs + Sinkhorn + payments =================
// 256 threads = 4 waves, 64 rows/block (4 m-tiles). N-SPLIT as round 9.
// aug f32 overlay now uses ROW STRIDE 260 (was 256): 260 mod 32 = 4 breaks the
// 16-way bank conflict on the Sinkhorn K-load (-> 8-way, float4 floor) and the
// 4-way conflict on aug stores (-> 2-way, free).
// LDS: [0,32KB) act_a, [32,64KB) act_p, aug overlay [0, 66560B) stride-260,
//      frac f32 [66560, 70656).  70656 B -> 2 blocks/CU = 8 waves/CU.
__global__ __launch_bounds__(256, 2) void fused_kernel(
  const float* __restrict__ X, const _Float16* __restrict__ WT,
  const float* __restrict__ ab0, const float* __restrict__ ab1,
  const float* __restrict__ ab2, const float* __restrict__ ab3,
  const float* __restrict__ pb0, const float* __restrict__ pb1,
  const float* __restrict__ pb2, const float* __restrict__ pb3,
  float* __restrict__ out)
{
  __shared__ unsigned int S[17664];   // 70656 B
  unsigned int* act_a = S;
  unsigned int* act_p = S + 8192;
  float* frac_l = (float*)(S + 16640);
  constexpr int AUGS = 260;                  // aug row stride (floats)
  const int t = threadIdx.x;
  const int w = t >> 6;                      // wave id 0..3
  const int l = t & 63, q = l>>4, l15 = l&15;
  const int nt0 = w*2;                       // n-tile base for 128-wide layers
  const long rb = (long)blockIdx.x * 64;

  // epilogue maker: bias+tanh+pack all 4 m-tiles at global n-tile ntg
  auto epi_act = [&](unsigned int* act, const float* bias, bool lo){
    return [=](int ntg, auto& acc){
      float bb = bias[ntg*16 + l15];
#pragma unroll
      for (int m=0; m<4; ++m){
#pragma unroll
        for (int r=0; r<4; ++r){
          float tv = tanh_f(acc[m][r] + bb);
          act[aaddr(m*16 + q*4 + r, ntg*16 + l15)] = lo ? pack_act(tv) : pack_act_hi(tv);
        }
      }
    };
  };

  // ---- L1 of both nets: X frags for all 4 m-tiles (K=256), own 2 n-tiles ----
  {
    half8 Xf[4][8];
#pragma unroll
    for (int mt=0; mt<4; ++mt){
      float4 xa[8], xb[8];
#pragma unroll
      for (int ks=0; ks<8; ++ks){
        const float* xp = X + (rb + mt*16 + l15)*256 + ks*32 + q*8;
        xa[ks] = *(const float4*)(xp);
        xb[ks] = *(const float4*)(xp + 4);
      }
#pragma unroll
      for (int ks=0; ks<8; ++ks){
        half8 h;
        h[0]=(_Float16)xa[ks].x; h[1]=(_Float16)xa[ks].y; h[2]=(_Float16)xa[ks].z; h[3]=(_Float16)xa[ks].w;
        h[4]=(_Float16)xb[ks].x; h[5]=(_Float16)xb[ks].y; h[6]=(_Float16)xb[ks].z; h[7]=(_Float16)xb[ks].w;
        Xf[mt][ks] = h;
      }
    }
    mfma_stream4<8,1,2,2>(Xf, Xf, WT+O_AW0H, WT+O_AW0H, 256, nt0, l15, q,
                          epi_act(act_a, ab0, true));
    mfma_stream4<8,1,2,2>(Xf, Xf, WT+O_PW0H, WT+O_PW0H, 256, nt0, l15, q,
                          epi_act(act_p, pb0, false));
  }
  __syncthreads();

  // ---- hidden stages: read-a|bar|a-stream|read-p|bar|p-stream|bar ----
#pragma unroll 1
  for (int st=0; st<2; ++st){
    const _Float16* Wah = WT + (st ? O_AW2H : O_AW1H);
    const _Float16* Wal = WT + (st ? O_AW2L : O_AW1L);
    const _Float16* Wph = WT + (st ? O_PW2H : O_PW1H);
    const float* ba = st ? ab2 : ab1;
    const float* bp = st ? pb2 : pb1;
    {
      half8 Fah[4][4], Fal[4][4];
#pragma unroll
      for (int m=0; m<4; ++m)
#pragma unroll
        for (int ks=0; ks<4; ++ks)
          read_frag<true>(act_a, m*16 + l15, ks, q, Fah[m][ks], Fal[m][ks]);
      __syncthreads();
      mfma_stream4<4,3,2,2>(Fah, Fal, Wah, Wal, 128, nt0, l15, q,
                            epi_act(act_a, ba, true));
    }
    {
      half8 Fph[4][4], du;
#pragma unroll
      for (int m=0; m<4; ++m)
#pragma unroll
        for (int ks=0; ks<4; ++ks)
          read_frag<false>(act_p, m*16 + l15, ks, q, Fph[m][ks], du);
      __syncthreads();
      mfma_stream4<4,1,2,3>(Fph, Fph, Wph, Wph, 128, nt0, l15, q,
                            epi_act(act_p, bp, false));
    }
    __syncthreads();
  }

  // ---- final stage: pre-read frags, bar; pL4 (wave0) + aL4 quarter -> aug ----
  {
    half8 Fah[4][4], Fal[4][4], Fph[4][4], du;
#pragma unroll
    for (int m=0; m<4; ++m)
#pragma unroll
      for (int ks=0; ks<4; ++ks)
        read_frag<true>(act_a, m*16 + l15, ks, q, Fah[m][ks], Fal[m][ks]);
    if (w == 0){
#pragma unroll
      for (int m=0; m<4; ++m)
#pragma unroll
        for (int ks=0; ks<4; ++ks)
          read_frag<false>(act_p, m*16 + l15, ks, q, Fph[m][ks], du);
    }
    __syncthreads();
    if (w == 0){
      mfma_stream4<4,1,1,2>(Fph, Fph, WT+O_PW3H, WT+O_PW3H, 128, 0, l15, q,
        [&](int, auto& acc){
          float bb = pb3[l15];
#pragma unroll
          for (int m=0; m<4; ++m)
#pragma unroll
            for (int r=0; r<4; ++r)
              frac_l[(m*16 + q*4 + r)*16 + l15] = sigmoid_f(acc[m][r] + bb);
        });
    }
    // aug quarter: wave w owns cols w*64..w*64+63; stride-260 overlay of act_a/p
    float* augl = (float*)S;
    const int ncol0 = w*64;
    mfma_stream4<4,3,4,2>(Fah, Fal,
                          WT+O_AW3H + ncol0*128, WT+O_AW3L + ncol0*128,
                          128, 0, l15, q,
      [&](int nt, auto& acc){
        float bb = ab3[ncol0 + nt*16 + l15];
#pragma unroll
        for (int m=0; m<4; ++m)
#pragma unroll
          for (int r=0; r<4; ++r)
            augl[(m*16 + q*4 + r)*AUGS + ncol0 + nt*16 + l15] = acc[m][r] + bb;
      });
    __syncthreads();
  }

  // ================= Sinkhorn + payments: wave w owns elements w*16..w*16+15 ==
  const int c = l & 3;
  const float Ssc = 14.426950408889634f; // (1/EPS)/ln2 : logits in exp2 units
  const float cmask = (c == 3) ? 1.0f : 0.0f;
  const int eL = w*16 + (l >> 2);
  const long e = rb + eL;

  floatx2 Kp[4][8];   // owned columns, rows (2k, 2k+1)
  floatx2 KPp[8];     // pad column 16 (lane 3 only; zero elsewhere), row-pairs

  const float* ap = (const float*)S + eL*AUGS + 4*c;
#pragma unroll
  for (int k=0;k<8;++k){
    float4 va = *(const float4*)(ap + (2*k  )*16);
    float4 vb = *(const float4*)(ap + (2*k+1)*16);
    Kp[0][k] = (floatx2){va.x*Ssc, vb.x*Ssc};
    Kp[1][k] = (floatx2){va.y*Ssc, vb.y*Ssc};
    Kp[2][k] = (floatx2){va.z*Ssc, vb.z*Ssc};
    Kp[3][k] = (floatx2){va.w*Ssc, vb.w*Ssc};
  }

  // max-subtract + exponentiate (row-wise, across the 4 lanes + pad col 0)
#pragma unroll
  for (int k=0;k<8;++k){
    float m0 = fmaxf(fmaxf(Kp[0][k].x,Kp[1][k].x), fmaxf(Kp[2][k].x,Kp[3][k].x));
    m0 = qmax2(fmaxf(m0, 0.0f));
    float m1 = fmaxf(fmaxf(Kp[0][k].y,Kp[1][k].y), fmaxf(Kp[2][k].y,Kp[3][k].y));
    m1 = qmax2(fmaxf(m1, 0.0f));
    Kp[0][k] = (floatx2){exp2_f(Kp[0][k].x-m0), exp2_f(Kp[0][k].y-m1)};
    Kp[1][k] = (floatx2){exp2_f(Kp[1][k].x-m0), exp2_f(Kp[1][k].y-m1)};
    Kp[2][k] = (floatx2){exp2_f(Kp[2][k].x-m0), exp2_f(Kp[2][k].y-m1)};
    Kp[3][k] = (floatx2){exp2_f(Kp[3][k].x-m0), exp2_f(Kp[3][k].y-m1)};
    KPp[k]   = (floatx2){cmask*exp2_f(-m0), cmask*exp2_f(-m1)};
  }
  // row 16: logits all 0, row max = 0 -> K entries exactly 1 (pad col: cmask)

  float vj0=1.f, vj1=1.f, vj2=1.f, vj3=1.f;
  float v16 = cmask;
  floatx2 u2[8];
  float u16;

  for (int r=0;r<40;++r){
    floatx2 b0=(floatx2){vj0,vj0}, b1=(floatx2){vj1,vj1};
    floatx2 b2=(floatx2){vj2,vj2}, b3=(floatx2){vj3,vj3};
    floatx2 b16=(floatx2){v16,v16};
    // ---- row normalization: u_i = 1 / sum_j K_ij v_j ----
#pragma unroll
    for (int k=0;k<8;++k){
      floatx2 pp = pk_mul2(Kp[0][k], b0);
      pp = pk_fma2(Kp[1][k], b1, pp);
      pp = pk_fma2(Kp[2][k], b2, pp);
      pp = pk_fma2(Kp[3][k], b3, pp);
      pp = pk_fma2(KPp[k], b16, pp);
      float px = qadd2(pp.x);
      float py = qadd2(pp.y);
      u2[k] = (floatx2){rcp_f(px), rcp_f(py)};
    }
    {
      // row 16: K == 1 across real cols, cmask on pad col; a_16 = I = 16
      float p16 = (vj0+vj1) + (vj2+vj3) + cmask*v16;
      p16 = qadd2(p16);
      u16 = 16.0f * rcp_f(p16);
    }
    // ---- column normalization: v_j = 1 / sum_i K_ij u_i ----
    floatx2 t0p = pk_mul2(Kp[0][0], u2[0]);
    floatx2 t1p = pk_mul2(Kp[1][0], u2[0]);
    floatx2 t2p = pk_mul2(Kp[2][0], u2[0]);
    floatx2 t3p = pk_mul2(Kp[3][0], u2[0]);
    floatx2 tPp = pk_mul2(KPp[0],   u2[0]);
#pragma unroll
    for (int k=1;k<8;++k){
      t0p = pk_fma2(Kp[0][k], u2[k], t0p);
      t1p = pk_fma2(Kp[1][k], u2[k], t1p);
      t2p = pk_fma2(Kp[2][k], u2[k], t2p);
      t3p = pk_fma2(Kp[3][k], u2[k], t3p);
      tPp = pk_fma2(KPp[k],   u2[k], tPp);
    }
    float t0 = t0p.x + t0p.y + u16;        // row-16 K == 1
    float t1 = t1p.x + t1p.y + u16;
    float t2 = t2p.x + t2p.y + u16;
    float t3 = t3p.x + t3p.y + u16;
    float t16 = tPp.x + tPp.y + cmask*u16;
    vj0 = rcp_f(t0); vj1 = rcp_f(t1); vj2 = rcp_f(t2); vj3 = rcp_f(t3);
    v16 = cmask * 16.0f * rcp_f(t16 + 1e-30f + (1.0f - cmask));  // b_16 = A = 16; NaN-guard off-lane
  }

  // ---- allocs = u_i K_ij v_j (write) + payments dot fused (reuse w) ----
  float* op = out + e*256 + 4*c;
  const float* bpx = X + e*256 + 4*c;
  float pv0=0.f, pv1=0.f, pv2=0.f, pv3=0.f;
#pragma unroll
  for (int k=0;k<8;++k){
#pragma unroll
    for (int h=0;h<2;++h){
      const int i = 2*k + h;
      const float uu = h ? u2[k].y : u2[k].x;
      const float K0 = h ? Kp[0][k].y : Kp[0][k].x;
      const float K1 = h ? Kp[1][k].y : Kp[1][k].x;
      const float K2 = h ? Kp[2][k].y : Kp[2][k].x;
      const float K3 = h ? Kp[3][k].y : Kp[3][k].x;
      float4 wv;
      wv.x = uu*K0*vj0;
      wv.y = uu*K1*vj1;
      wv.z = uu*K2*vj2;
      wv.w = uu*K3*vj3;
      *(float4*)(op + i*16) = wv;
      float4 bb = *(const float4*)(bpx + i*16);
      float s = wv.x*bb.x + wv.y*bb.y + wv.z*bb.z + wv.w*bb.w;
      s = qadd2(s);
      if ((i>>2) == c){
        const int rr = i & 3;
        if      (rr==0) pv0 = s;
        else if (rr==1) pv1 = s;
        else if (rr==2) pv2 = s;
        else            pv3 = s;
      }
    }
  }
  const float4 fr = *(const float4*)(frac_l + eL*16 + 4*c);
  float4 pvv;
  pvv.x = pv0*fr.x; pvv.y = pv1*fr.y; pvv.z = pv2*fr.z; pvv.w = pv3*fr.w;
  *(float4*)(out + (size_t)NB*256 + e*16 + 4*c) = pvv;
}

// ================= launch =================
extern "C" void kernel_launch(void* const* d_in, const int* in_sizes, int n_in,
                              void* d_out, int out_size, void* d_ws, size_t ws_size,
                              hipStream_t stream)
{
  const float* bids = (const float*)d_in[0];
  const float* aw0 = (const float*)d_in[1];  const float* ab0 = (const float*)d_in[2];
  const float* aw1 = (const float*)d_in[3];  const float* ab1 = (const float*)d_in[4];
  const float* aw2 = (const float*)d_in[5];  const float* ab2 = (const float*)d_in[6];
  const float* aw3 = (const float*)d_in[7];  const float* ab3 = (const float*)d_in[8];
  const float* pw0 = (const float*)d_in[9];  const float* pb0 = (const float*)d_in[10];
  const float* pw1 = (const float*)d_in[11]; const float* pb1 = (const float*)d_in[12];
  const float* pw2 = (const float*)d_in[13]; const float* pb2 = (const float*)d_in[14];
  const float* pw3 = (const float*)d_in[15]; const float* pb3 = (const float*)d_in[16];

  _Float16* WT = (_Float16*)d_ws;

  // PrepJob: {src, h, l, K, N} where src is K x N row-major, dst is N x K
  PrepJobs js;
  js.j[0] = { aw0, WT+O_AW0H, nullptr,   256, 128 };
  js.j[1] = { aw1, WT+O_AW1H, WT+O_AW1L, 128, 128 };
  js.j[2] = { aw2, WT+O_AW2H, WT+O_AW2L, 128, 128 };
  js.j[3] = { aw3, WT+O_AW3H, WT+O_AW3L, 128, 256 };
  js.j[4] = { pw0, WT+O_PW0H, nullptr,   256, 128 };
  js.j[5] = { pw1, WT+O_PW1H, nullptr,   128, 128 };
  js.j[6] = { pw2, WT+O_PW2H, nullptr,   128, 128 };
  js.j[7] = { pw3, WT+O_PW3H, nullptr,   128,  16 };

  // max tiles over jobs: (256/64)*(128/64)=8 (aw0/pw0), (128/64)*(256/64)=8 (aw3)
  prep_kernel<<<dim3(8,8), 256, 0, stream>>>(js);
  fused_kernel<<<dim3(NB/64), 256, 0, stream>>>(bids, WT, ab0,ab1,ab2,ab3,
                                                pb0,pb1,pb2,pb3, (float*)d_out);
}